// Round 8
// baseline (725.808 us; speedup 1.0000x reference)
//
#include <hip/hip_runtime.h>

typedef unsigned short u16;
typedef unsigned int u32;
typedef __attribute__((ext_vector_type(8))) short short8;
typedef __attribute__((ext_vector_type(4))) float floatx4;

__device__ __forceinline__ float bf2f(u16 x) {
    union { u32 u; float f; } c; c.u = ((u32)x) << 16; return c.f;
}
__device__ __forceinline__ u16 f2bf(float f) {
    union { float f; u32 u; } c; c.f = f;
    return (u16)((c.u + 0x7FFFu + ((c.u >> 16) & 1u)) >> 16);
}

// async global->LDS, 16B per lane. LDS dest = wave-uniform base + lane*16.
#define GLD_LDS(g, l) __builtin_amdgcn_global_load_lds( \
    (const __attribute__((address_space(1))) u32*)(g),  \
    (__attribute__((address_space(3))) u32*)(l), 16, 0, 0)

// ---------------- f32 -> bf16 convert (optional fused relu) ----------------

__global__ void cvt_kernel(const float* __restrict__ src, u16* __restrict__ dst,
                           int n8, int do_relu) {
    int i = blockIdx.x * 256 + threadIdx.x;
    if (i >= n8) return;
    float4 a = ((const float4*)src)[2 * i];
    float4 b = ((const float4*)src)[2 * i + 1];
    float v[8] = {a.x, a.y, a.z, a.w, b.x, b.y, b.z, b.w};
    short8 o;
#pragma unroll
    for (int j = 0; j < 8; j++) {
        float x = v[j];
        if (do_relu) x = fmaxf(x, 0.f);
        o[j] = (short)f2bf(x);
    }
    ((short8*)dst)[i] = o;
}

// ---------------- stats / gates (pure f32) ----------------

// column mean over sequence: x [B,N,1024] f32 -> out [B*1024] f32 (pre-zeroed)
__global__ void mean_kernel(const float* __restrict__ x, float* __restrict__ out,
                            int N, int chunk) {
    int idx = blockIdx.x * 256 + threadIdx.x;   // (b,d) in [0, 8192)
    int b = idx >> 10, d = idx & 1023;
    int nlo = blockIdx.y * chunk;
    const float* p = x + (size_t)b * N * 1024 + (size_t)nlo * 1024 + d;
    float s = 0.f;
    for (int n = 0; n < chunk; n++) s += p[(size_t)n * 1024];
    atomicAdd(out + idx, s * (1.0f / (float)N));
}

// gate[b,n] = 1 + sigmoid( relu(mean[b,:]) . Wg[n,:] + bg[n] ), one wave/output
__global__ __launch_bounds__(256) void gate_kernel(const float* __restrict__ mean,
                                                   const float* __restrict__ Wg,
                                                   const float* __restrict__ bg,
                                                   float* __restrict__ gout) {
    int gw = blockIdx.x * 4 + (threadIdx.x >> 6);   // [0, 8192)
    int lane = threadIdx.x & 63;
    int b = gw >> 10, n = gw & 1023;
    const float* wr = Wg + (size_t)n * 1024;
    const float* mr = mean + b * 1024;
    float acc = 0.f;
    for (int k = lane; k < 1024; k += 64)
        acc += fmaxf(mr[k], 0.f) * wr[k];
#pragma unroll
    for (int m = 1; m < 64; m <<= 1) acc += __shfl_xor(acc, m, 64);
    if (lane == 0) {
        float xg = acc + bg[n];
        gout[gw] = 1.f + 1.f / (1.f + __expf(-xg));
    }
}

// residual: c_bf16[i] = a_f32[i] + b_bf16[i]
__global__ void add_kernel(const float* __restrict__ a, const u16* __restrict__ b,
                           u16* __restrict__ c, int n) {
    int i = blockIdx.x * 256 + threadIdx.x;
    if (i >= n) return;
    c[i] = f2bf(a[i] + bf2f(b[i]));
}

// ---------------- GEMM: C[M,N] = A[M,K] . W[N,K]^T + bias, optional (1+gate) ----------------
// A, W bf16 (pre-converted in ws). 128x128 tile, BK=32, 4 waves (2x2), each
// wave 4x4 MFMA 16x16x32. m97-style GLD_LDS staging (value-validated r2==r3).
// Output: bf16 (Ch) or f32 (Cf), exactly one non-null.

__global__ __launch_bounds__(256) void gemm_bt_kernel(
    const u16* __restrict__ A, const u16* __restrict__ W,
    const float* __restrict__ bias, const float* __restrict__ gate,
    u16* __restrict__ Ch, float* __restrict__ Cf,
    int M, int N, int K, int seq, int gateN)
{
    __shared__ u16 As[128 * 32];   // [m][k] row-major, 8 KB
    __shared__ u16 Bs[128 * 32];   // [n][k] row-major, 8 KB

    const int tid = threadIdx.x;
    const int wave = tid >> 6, lane = tid & 63, quad = lane >> 4, l15 = lane & 15;
    const int m0 = blockIdx.y * 128, n0 = blockIdx.x * 128;
    const int wm = (wave >> 1) * 64, wn = (wave & 1) * 64;

    floatx4 acc[4][4] = {};

    // staging map: round r covers tile bytes [r*4096 + wave*1024 + lane*16, +16)
    const int e0 = (wave * 1024 + lane * 16) >> 1;       // elements, round 0
    const int sr0 = e0 >> 5, sc0 = e0 & 31;
    const int e1 = e0 + 2048;                            // round 1
    const int sr1 = e1 >> 5, sc1 = e1 & 31;
    const size_t aoff0 = (size_t)(m0 + sr0) * K + sc0;
    const size_t aoff1 = (size_t)(m0 + sr1) * K + sc1;
    const size_t boff0 = (size_t)(n0 + sr0) * K + sc0;
    const size_t boff1 = (size_t)(n0 + sr1) * K + sc1;

    for (int k0 = 0; k0 < K; k0 += 32) {
        GLD_LDS(A + aoff0 + k0, As + wave * 512);
        GLD_LDS(A + aoff1 + k0, As + 2048 + wave * 512);
        GLD_LDS(W + boff0 + k0, Bs + wave * 512);
        GLD_LDS(W + boff1 + k0, Bs + 2048 + wave * 512);
        __syncthreads();

        short8 af[4], bfr[4];
#pragma unroll
        for (int i = 0; i < 4; i++) {
            af[i]  = *(const short8*)(As + (wm + i * 16 + l15) * 32 + quad * 8);
            bfr[i] = *(const short8*)(Bs + (wn + i * 16 + l15) * 32 + quad * 8);
        }
#pragma unroll
        for (int mi = 0; mi < 4; mi++)
#pragma unroll
            for (int ni = 0; ni < 4; ni++)
                acc[mi][ni] = __builtin_amdgcn_mfma_f32_16x16x32_bf16(af[mi], bfr[ni], acc[mi][ni], 0, 0, 0);
        __syncthreads();
    }

    const int b = m0 / seq;
#pragma unroll
    for (int ni = 0; ni < 4; ni++) {
        const int ncol = n0 + wn + ni * 16 + l15;
        const float bsv = bias[ncol];
        float g = 1.f;
        if (gate != nullptr && ncol < gateN) g = gate[b * 1024 + (ncol & 1023)];
#pragma unroll
        for (int mi = 0; mi < 4; mi++) {
            const int row = m0 + wm + mi * 16 + quad * 4;
#pragma unroll
            for (int r = 0; r < 4; r++) {
                float val = (acc[mi][ni][r] + bsv) * g;
                size_t idx = (size_t)(row + r) * N + ncol;
                if (Cf) Cf[idx] = val; else Ch[idx] = f2bf(val);
            }
        }
    }
}

// ---------------- fused flash attention (value-validated in r2) ----------------
// T: [B, N, 3072] bf16 gated trans (k | q | v thirds, 8 heads x 128 each).
// U: [B, N, 1024] bf16 update. Block = (128 q-rows, b*8+h). 4 waves x 32 rows.

__global__ __launch_bounds__(256) void attn_kernel(
    const u16* __restrict__ T, u16* __restrict__ U, int N)
{
    __shared__ u16 Ks[4096];      // chunked: [c][kv][32] -> c*1024 + kv*32 + dlo
    __shared__ u16 Vs[4096];      // transposed: [d][kv] -> d*32 + kv
    __shared__ u16 Ps[4][1024];   // per-wave 32x32 P

    const int tid = threadIdx.x;
    const int wave = tid >> 6, lane = tid & 63, quad = lane >> 4, l15 = lane & 15;
    const int qb = blockIdx.x;
    const int b = blockIdx.y >> 3, h = blockIdx.y & 7;

    const size_t base = (size_t)b * N * 3072;
    const int kcol = h * 128, qcol = 1024 + h * 128, vcol = 2048 + h * 128;

    short8 qf[2][4];
    const int qrow0 = qb * 128 + wave * 32;
#pragma unroll
    for (int mi = 0; mi < 2; mi++)
#pragma unroll
        for (int c = 0; c < 4; c++)
            qf[mi][c] = *(const short8*)(T + base + (size_t)(qrow0 + mi * 16 + l15) * 3072
                                           + qcol + c * 32 + quad * 8);

    floatx4 o[2][8] = {};
    float mrow[2][4], lrow[2][4];
#pragma unroll
    for (int mi = 0; mi < 2; mi++)
#pragma unroll
        for (int r = 0; r < 4; r++) { mrow[mi][r] = -1e30f; lrow[mi][r] = 0.f; }

    const float scale = 0.08838834764831845f;  // 1/sqrt(128)

    int kst_kv[2], kst_d[2];
#pragma unroll
    for (int r = 0; r < 2; r++) {
        int ob = r * 4096 + wave * 1024 + lane * 16;
        int c = ob >> 11, rem = ob & 2047;
        kst_kv[r] = rem >> 6;
        kst_d[r] = c * 32 + ((rem & 63) >> 1);
    }
    const int kvp = tid >> 4, d8 = tid & 15;

    for (int kt = 0; kt < N; kt += 32) {
#pragma unroll
        for (int r = 0; r < 2; r++)
            GLD_LDS(T + base + (size_t)(kt + kst_kv[r]) * 3072 + kcol + kst_d[r],
                    Ks + r * 2048 + wave * 512);
        {
            const u16* vp0 = T + base + (size_t)(kt + 2 * kvp) * 3072 + vcol + d8 * 8;
            short8 v0 = *(const short8*)vp0;
            short8 v1 = *(const short8*)(vp0 + 3072);
#pragma unroll
            for (int j = 0; j < 8; j++) {
                u32 w = ((u32)(u16)v0[j]) | (((u32)(u16)v1[j]) << 16);
                *(u32*)(Vs + (d8 * 8 + j) * 32 + 2 * kvp) = w;
            }
        }
        __syncthreads();

        float p[2][2][4];
#pragma unroll
        for (int ni = 0; ni < 2; ni++) {
            short8 kf[4];
#pragma unroll
            for (int c = 0; c < 4; c++)
                kf[c] = *(const short8*)(Ks + c * 1024 + (ni * 16 + l15) * 32 + quad * 8);
#pragma unroll
            for (int mi = 0; mi < 2; mi++) {
                floatx4 s = {0.f, 0.f, 0.f, 0.f};
#pragma unroll
                for (int c = 0; c < 4; c++)
                    s = __builtin_amdgcn_mfma_f32_16x16x32_bf16(qf[mi][c], kf[c], s, 0, 0, 0);
#pragma unroll
                for (int r = 0; r < 4; r++) p[mi][ni][r] = s[r] * scale;
            }
        }

#pragma unroll
        for (int mi = 0; mi < 2; mi++)
#pragma unroll
            for (int r = 0; r < 4; r++) {
                float tm = fmaxf(p[mi][0][r], p[mi][1][r]);
#pragma unroll
                for (int msk = 1; msk < 16; msk <<= 1) tm = fmaxf(tm, __shfl_xor(tm, msk, 64));
                float mnew = fmaxf(mrow[mi][r], tm);
                float alpha = __expf(mrow[mi][r] - mnew);
                mrow[mi][r] = mnew;
                float p0 = __expf(p[mi][0][r] - mnew);
                float p1 = __expf(p[mi][1][r] - mnew);
                p[mi][0][r] = p0; p[mi][1][r] = p1;
                float ps = p0 + p1;
#pragma unroll
                for (int msk = 1; msk < 16; msk <<= 1) ps += __shfl_xor(ps, msk, 64);
                lrow[mi][r] = lrow[mi][r] * alpha + ps;
#pragma unroll
                for (int nt = 0; nt < 8; nt++) o[mi][nt][r] *= alpha;
            }

#pragma unroll
        for (int mi = 0; mi < 2; mi++)
#pragma unroll
            for (int ni = 0; ni < 2; ni++)
#pragma unroll
                for (int r = 0; r < 4; r++)
                    Ps[wave][(mi * 16 + quad * 4 + r) * 32 + ni * 16 + l15] = f2bf(p[mi][ni][r]);

        short8 pf[2];
#pragma unroll
        for (int mi = 0; mi < 2; mi++)
            pf[mi] = *(const short8*)(&Ps[wave][(mi * 16 + l15) * 32 + quad * 8]);

#pragma unroll
        for (int nt = 0; nt < 8; nt++) {
            short8 vf = *(const short8*)(Vs + (nt * 16 + l15) * 32 + quad * 8);
#pragma unroll
            for (int mi = 0; mi < 2; mi++)
                o[mi][nt] = __builtin_amdgcn_mfma_f32_16x16x32_bf16(pf[mi], vf, o[mi][nt], 0, 0, 0);
        }
        __syncthreads();
    }

    const size_t ub = (size_t)b * N * 1024;
#pragma unroll
    for (int mi = 0; mi < 2; mi++)
#pragma unroll
        for (int r = 0; r < 4; r++) {
            float inv = 1.f / lrow[mi][r];
            const size_t row = qb * 128 + wave * 32 + mi * 16 + quad * 4 + r;
#pragma unroll
            for (int nt = 0; nt < 8; nt++)
                U[ub + row * 1024 + h * 128 + nt * 16 + l15] = f2bf(o[mi][nt][r] * inv);
        }
}

// ---------------- launch ----------------
// Inputs f32, outputs f32 (both per reference dtypes). ws peak = 80.1 MB:
// stats 128 KB | weights 8 MB @1MB | activations 16 MB @16MB | trans 48 MB @32MB.
// q phase then v phase reuse the same regions sequentially.

extern "C" void kernel_launch(void* const* d_in, const int* in_sizes, int n_in,
                              void* d_out, int out_size, void* d_ws, size_t ws_size,
                              hipStream_t stream) {
    (void)in_sizes; (void)n_in; (void)out_size; (void)ws_size;
    const float* v   = (const float*)d_in[0];
    const float* q   = (const float*)d_in[1];
    const float* Wg_v4q = (const float*)d_in[2];
    const float* bg_v4q = (const float*)d_in[3];
    const float* Wg_q4v = (const float*)d_in[4];
    const float* bg_q4v = (const float*)d_in[5];
    const float* Wv  = (const float*)d_in[6];
    const float* bv  = (const float*)d_in[7];
    const float* Wq  = (const float*)d_in[8];
    const float* bq  = (const float*)d_in[9];
    const float* Wvo = (const float*)d_in[10];
    const float* bvo = (const float*)d_in[11];
    const float* Wqo = (const float*)d_in[12];
    const float* bqo = (const float*)d_in[13];
    float* out = (float*)d_out;                     // [v: 8388608][q: 4194304] f32

    char* w = (char*)d_ws;
    float* vmean = (float*)(w + 0);                 // 32 KB
    float* qmean = (float*)(w + 32768);
    float* gv4q  = (float*)(w + 65536);
    float* gq4v  = (float*)(w + 98304);
    u16* cWt  = (u16*)(w + (1 << 20));              // 6 MB (trans weight bf16)
    u16* cWo  = (u16*)(w + (1 << 20) + 6291456);    // 2 MB (proj weight bf16)
    u16* aReg = (u16*)(w + (16 << 20));             // 16 MB (relu acts / updates)
    u16* tReg = (u16*)(w + (32 << 20));             // 48 MB (trans / residual sum)

    // stats + gates
    hipMemsetAsync(vmean, 0, 65536, stream);        // covers vmean + qmean
    mean_kernel<<<dim3(32, 8), 256, 0, stream>>>(v, vmean, 1024, 128);
    mean_kernel<<<dim3(32, 8), 256, 0, stream>>>(q, qmean, 512, 64);
    gate_kernel<<<2048, 256, 0, stream>>>(vmean, Wg_v4q, bg_v4q, gv4q);  // for q pipeline
    gate_kernel<<<2048, 256, 0, stream>>>(qmean, Wg_q4v, bg_q4v, gq4v);  // for v pipeline

    // ---- q phase ----
    u16* crq  = aReg;                               // bf16 relu(q), 8 MB
    u16* qt   = tReg;                               // [8,512,3072] bf16, 24 MB
    u16* qupd = aReg;                               // reuses crq after trans GEMM
    u16* qsum = tReg;                               // reuses qt after attention
    cvt_kernel<<<2048, 256, 0, stream>>>(q, crq, 524288, 1);
    cvt_kernel<<<1536, 256, 0, stream>>>(Wq, cWt, 393216, 0);
    cvt_kernel<<<512, 256, 0, stream>>>(Wqo, cWo, 131072, 0);
    gemm_bt_kernel<<<dim3(24, 32), 256, 0, stream>>>(crq, cWt, bq, gv4q, qt, nullptr,
                                                     4096, 3072, 1024, 512, 2048);
    attn_kernel<<<dim3(4, 64), 256, 0, stream>>>(qt, qupd, 512);
    add_kernel<<<16384, 256, 0, stream>>>(q, qupd, qsum, 4194304);
    gemm_bt_kernel<<<dim3(8, 32), 256, 0, stream>>>(qsum, cWo, bqo, nullptr, nullptr,
                                                    out + 8388608, 4096, 1024, 1024, 512, 0);

    // ---- v phase ----
    u16* crv  = aReg;                               // bf16 relu(v), 16 MB
    u16* vt   = tReg;                               // [8,1024,3072] bf16, 48 MB
    u16* vupd = aReg;
    u16* vsum = tReg;
    cvt_kernel<<<4096, 256, 0, stream>>>(v, crv, 1048576, 1);
    cvt_kernel<<<1536, 256, 0, stream>>>(Wv, cWt, 393216, 0);
    cvt_kernel<<<512, 256, 0, stream>>>(Wvo, cWo, 131072, 0);
    gemm_bt_kernel<<<dim3(24, 64), 256, 0, stream>>>(crv, cWt, bv, gq4v, vt, nullptr,
                                                     8192, 3072, 1024, 1024, 2048);
    attn_kernel<<<dim3(8, 64), 256, 0, stream>>>(vt, vupd, 1024);
    add_kernel<<<32768, 256, 0, stream>>>(v, vupd, vsum, 8388608);
    gemm_bt_kernel<<<dim3(8, 64), 256, 0, stream>>>(vsum, cWo, bvo, nullptr, nullptr,
                                                    out, 8192, 1024, 1024, 1024, 0);
}